// Round 3
// baseline (1812.560 us; speedup 1.0000x reference)
//
#include <hip/hip_runtime.h>
#include <hip/hip_bf16.h>

// Problem dims (fixed by reference): D=512, B=32, S_c=256, S_q(T)=32
#define DIMD 512
#define NB   32
#define NS   256
#define NT   32

typedef __bf16 bf16x8 __attribute__((ext_vector_type(8)));
typedef float  f32x4  __attribute__((ext_vector_type(4)));

__device__ __forceinline__ float tanh_fast(float x) {
    float e = __expf(2.f * x);
    return 1.f - 2.f / (e + 1.f);
}

// async global->LDS, 16B per lane; lds dest = wave-uniform base + lane*16
__device__ __forceinline__ void gl_lds16(const __bf16* g, __bf16* l) {
    __builtin_amdgcn_global_load_lds((const __attribute__((address_space(1))) void*)g,
                                     (__attribute__((address_space(3))) void*)l, 16, 0, 0);
}

// ---------------- prep kernels ----------------

__global__ void k_prep_acat(const float* __restrict__ ctxin, const float* __restrict__ img,
                            __bf16* __restrict__ acat) {
    int row = blockIdx.x;           // b*256+s
    int b = row >> 8, s = row & 255;
    const float* c  = ctxin + ((size_t)s * NB + b) * DIMD;
    const float* im = img   + ((size_t)s * NB + b) * DIMD;
    __bf16* o = acat + (size_t)row * 1024;
    for (int d = threadIdx.x; d < DIMD; d += 256) {
        o[d]       = (__bf16)c[d];
        o[512 + d] = (__bf16)im[d];
    }
}

__global__ void k_cvt_bf16(const float* __restrict__ in, __bf16* __restrict__ out, int n) {
    for (int i = blockIdx.x * blockDim.x + threadIdx.x; i < n; i += gridDim.x * blockDim.x)
        out[i] = (__bf16)in[i];
}

// dst[c][dOff + r] = src[r][c]  (512x512 fp32 -> bf16 transpose), dst row stride dstStride
__global__ void k_transpose_w(const float* __restrict__ src, __bf16* __restrict__ dst,
                              int dstStride, int dOff) {
    __shared__ float tile[32][33];
    int c0 = blockIdx.x * 32, r0 = blockIdx.y * 32;
    int x = threadIdx.x, y = threadIdx.y;   // x:0..31, y:0..7
#pragma unroll
    for (int k = 0; k < 32; k += 8)
        tile[y + k][x] = src[(size_t)(r0 + y + k) * DIMD + c0 + x];
    __syncthreads();
#pragma unroll
    for (int k = 0; k < 32; k += 8)
        dst[(size_t)(c0 + y + k) * dstStride + dOff + r0 + x] = (__bf16)tile[x][y + k];
}

// ---------------- LDS-staged bf16 MFMA GEMM (m97 pattern) ----------------
// C[M,N] = A[M,K] * BT[N,K]^T + bias1 (+bias2). Block 256 thr = 4 waves,
// tile 128x128, K-step 32. LDS tiles row-major [row][k], 64B rows (no pad:
// global_load_lds requires lane-contiguous dest).
__global__ void k_gemm_lds(const __bf16* __restrict__ A, const __bf16* __restrict__ BT,
                           const float* __restrict__ bias1, const float* __restrict__ bias2,
                           void* __restrict__ out, int M, int N, int K, int out_f32) {
    __shared__ __bf16 As[128 * 32];
    __shared__ __bf16 Bs[128 * 32];
    int tid = threadIdx.x, wave = tid >> 6, lane = tid & 63;
    int wm_ = wave >> 1, wn = wave & 1;
    int m0 = blockIdx.x * 128, n0 = blockIdx.y * 128;
    int lr = lane & 15, lq = lane >> 4;

    f32x4 acc[4][4];
#pragma unroll
    for (int i = 0; i < 4; i++)
#pragma unroll
        for (int j = 0; j < 4; j++) acc[i][j] = (f32x4){0.f, 0.f, 0.f, 0.f};

    // staging chunk ids: chunk g = (wave*2+i)*64 + lane covers row g>>2, k-quarter g&3
    int g0 = (wave * 2 + 0) * 64 + lane;
    int g1 = (wave * 2 + 1) * 64 + lane;
    int r0_ = g0 >> 2, c0_ = g0 & 3;
    int r1_ = g1 >> 2, c1_ = g1 & 3;
    __bf16* lbase0 = As + (wave * 2 + 0) * 512;   // +lane*16B added by HW
    __bf16* lbase1 = As + (wave * 2 + 1) * 512;
    __bf16* lbase2 = Bs + (wave * 2 + 0) * 512;
    __bf16* lbase3 = Bs + (wave * 2 + 1) * 512;

    for (int kk = 0; kk < K; kk += 32) {
        gl_lds16(A  + (size_t)(m0 + r0_) * K + kk + c0_ * 8, lbase0);
        gl_lds16(A  + (size_t)(m0 + r1_) * K + kk + c1_ * 8, lbase1);
        gl_lds16(BT + (size_t)(n0 + r0_) * K + kk + c0_ * 8, lbase2);
        gl_lds16(BT + (size_t)(n0 + r1_) * K + kk + c1_ * 8, lbase3);
        __syncthreads();
        bf16x8 af[4], bfv[4];
#pragma unroll
        for (int i = 0; i < 4; i++)
            af[i] = *(const bf16x8*)(As + (wm_ * 64 + i * 16 + lr) * 32 + lq * 8);
#pragma unroll
        for (int j = 0; j < 4; j++)
            bfv[j] = *(const bf16x8*)(Bs + (wn * 64 + j * 16 + lr) * 32 + lq * 8);
#pragma unroll
        for (int i = 0; i < 4; i++)
#pragma unroll
            for (int j = 0; j < 4; j++)
                acc[i][j] = __builtin_amdgcn_mfma_f32_16x16x32_bf16(af[i], bfv[j], acc[i][j], 0, 0, 0);
        __syncthreads();
    }

#pragma unroll
    for (int i = 0; i < 4; i++)
#pragma unroll
        for (int j = 0; j < 4; j++) {
            int col = n0 + wn * 64 + j * 16 + lr;
            float bs = bias1[col] + (bias2 ? bias2[col] : 0.f);
#pragma unroll
            for (int r = 0; r < 4; r++) {
                int row = m0 + wm_ * 64 + i * 16 + lq * 4 + r;   // verified C/D layout
                float v = acc[i][j][r] + bs;
                if (out_f32) ((float*)out)[(size_t)row * N + col] = v;
                else         ((__bf16*)out)[(size_t)row * N + col] = (__bf16)v;
            }
        }
}

// ---------------- scan: persistent kernel, per-batch barriers ----------------

// rm0 = b_rm (r=0), rrt0 = tanh(b_rr), barrier counters = 0
__global__ void k_init(const float* __restrict__ brm, const float* __restrict__ brr,
                       float* __restrict__ rm, float* __restrict__ rrt,
                       unsigned* __restrict__ ctr) {
    int b = blockIdx.x, e = threadIdx.x;
    rm[b * DIMD + e]  = brm[e];
    rrt[b * DIMD + e] = tanh_fast(brr[e]);
    if (e == 0) ctr[b] = 0;
}

// 8-block per-batch barrier: monotone counter, device-scope atomics + fences
__device__ __forceinline__ void bbar(unsigned* c, unsigned tgt) {
    __syncthreads();
    if (threadIdx.x == 0) {
        __threadfence();
        __hip_atomic_fetch_add(c, 1u, __ATOMIC_RELEASE, __HIP_MEMORY_SCOPE_AGENT);
        while (__hip_atomic_load(c, __ATOMIC_ACQUIRE, __HIP_MEMORY_SCOPE_AGENT) < tgt)
            __builtin_amdgcn_s_sleep(4);
        __threadfence();
    }
    __syncthreads();
}

// 256 blocks x 512 threads, persistent over all 32 scan steps.
// Batch b gets 8 blocks (co-located per XCD via blockIdx&7 swizzle).
// Per t: A) logits (distributed over s), bar, B) softmax + full r_new per
// block (redundant x8 -> no extra barrier), C) rm/rrt matvec (cols split
// over the 8 blocks, bf16 weights), bar.
__global__ __launch_bounds__(512, 2) void k_scan(
    const __bf16* __restrict__ ctxdm, const __bf16* __restrict__ ctx,
    const float* __restrict__ qm, const __bf16* __restrict__ Wrm,
    const __bf16* __restrict__ Wrr, const float* __restrict__ wms,
    const float* __restrict__ brm, const float* __restrict__ brr,
    float* __restrict__ logits, float* __restrict__ rm, float* __restrict__ rrt,
    float* __restrict__ rout, unsigned* __restrict__ ctr) {
    int x = blockIdx.x & 7, jj = blockIdx.x >> 3;
    int b = x * 4 + (jj >> 3), sub = jj & 7;
    int tid = threadIdx.x, wave = tid >> 6, lane = tid & 63;
    int e0 = lane * 8;

    float wm[8];
#pragma unroll
    for (int j = 0; j < 8; j++) wm[j] = wms[e0 + j];

    __shared__ float sp[256];
    __shared__ float part[8];
    __shared__ float srn[DIMD];
    __shared__ float sred[DIMD];

    unsigned tgt = 8;
    unsigned* cb = ctr + b;

    for (int t = 0; t < NT; t++) {
        // ---- phase A: logits for s in [sub*32, sub*32+32) ----
        float rrt_prev = rrt[b * DIMD + tid];   // read BEFORE bar1 (written after bar1 by C)
        float rq[8];
        {
            const float* rp = rm + (size_t)b * DIMD + e0;
            const float* qp = qm + ((size_t)t * NB + b) * DIMD + e0;
#pragma unroll
            for (int j = 0; j < 8; j++) rq[j] = rp[j] + qp[j];
        }
#pragma unroll
        for (int rr_ = 0; rr_ < 4; rr_++) {
            int s = sub * 32 + wave * 4 + rr_;
            bf16x8 cv = *(const bf16x8*)(ctxdm + ((size_t)(b * NS + s)) * DIMD + e0);
            float p_ = 0.f;
#pragma unroll
            for (int j = 0; j < 8; j++)
                p_ += tanh_fast((float)cv[j] + rq[j]) * wm[j];
#pragma unroll
            for (int off = 32; off; off >>= 1) p_ += __shfl_xor(p_, off);
            if (lane == 0) logits[b * NS + s] = p_;   // b_ms omitted: softmax shift-invariant
        }
        bbar(cb, tgt); tgt += 8;

        // ---- phase B: softmax + full r_new (redundant per block) ----
        float e = 0.f;
        if (tid < NS) { e = __expf(logits[b * NS + tid]); sp[tid] = e; }
        float wsum = e;
#pragma unroll
        for (int off = 32; off; off >>= 1) wsum += __shfl_xor(wsum, off);
        if (lane == 0) part[wave] = wsum;
        __syncthreads();
        float inv = 1.f / (part[0] + part[1] + part[2] + part[3]);

        float acc = 0.f;
        const __bf16* cp = ctx + ((size_t)b * NS) * DIMD + tid;
#pragma unroll 8
        for (int s = 0; s < NS; s++) acc = fmaf(sp[s], (float)cp[(size_t)s * DIMD], acc);
        float rn = acc * inv + rrt_prev;
        srn[tid] = rn;
        if (t == NT - 1 && sub == 0) rout[b * DIMD + tid] = rn;
        __syncthreads();

        // ---- phase C: rm/rrt matvec, cols [sub*64, sub*64+64) of each W ----
        {
            int k = tid >> 7, cl = tid & 127;          // k: d-quarter, cl: col task
            int col = sub * 64 + (cl & 63);
            const __bf16* Wp = (cl < 64) ? Wrm : Wrr;
            const __bf16* wc = Wp + (size_t)(k * 128) * DIMD + col;
            float a = 0.f;
#pragma unroll 8
            for (int d = 0; d < 128; d++)
                a = fmaf(srn[k * 128 + d], (float)wc[(size_t)d * DIMD], a);
            sred[cl * 4 + k] = a;
        }
        __syncthreads();
        if (tid < 128) {
            f32x4 v = *(const f32x4*)(sred + tid * 4);
            float s4 = v[0] + v[1] + v[2] + v[3];
            int c2 = sub * 64 + (tid & 63);
            if (tid < 64) rm[b * DIMD + c2]  = s4 + brm[c2];
            else          rrt[b * DIMD + c2] = tanh_fast(s4 + brr[c2]);
        }
        bbar(cb, tgt); tgt += 8;
    }
}

// g = r@W_rg + b_rg + qh@W_qg + b_qg   (64 blocks x 256 thr: 8 cols x 32 b each)
__global__ void k_final2(const float* __restrict__ r, const float* __restrict__ qh,
                         const float* __restrict__ Wrg, const float* __restrict__ Wqg,
                         const float* __restrict__ brg, const float* __restrict__ bqg,
                         float* __restrict__ out) {
    int cl = threadIdx.x & 7, b = threadIdx.x >> 3;
    int col = blockIdx.x * 8 + cl;
    const float* rp = r + (size_t)b * DIMD;
    const float* qp = qh + (size_t)b * DIMD;
    float acc = brg[col] + bqg[col];
#pragma unroll 4
    for (int d = 0; d < DIMD; d++)
        acc += rp[d] * Wrg[(size_t)d * DIMD + col] + qp[d] * Wqg[(size_t)d * DIMD + col];
    out[b * DIMD + col] = acc;
}

// ---------------- host ----------------

extern "C" void kernel_launch(void* const* d_in, const int* in_sizes, int n_in,
                              void* d_out, int out_size, void* d_ws, size_t ws_size,
                              hipStream_t stream) {
    const float* ctx_in = (const float*)d_in[0];
    const float* q_in   = (const float*)d_in[1];
    const float* qh     = (const float*)d_in[2];
    const float* img    = (const float*)d_in[3];
    const float* W_fc1  = (const float*)d_in[4];
    const float* b_fc1  = (const float*)d_in[5];
    const float* W_fc2  = (const float*)d_in[6];
    const float* b_fc2  = (const float*)d_in[7];
    const float* W_dm   = (const float*)d_in[8];
    const float* b_dm   = (const float*)d_in[9];
    const float* W_rm   = (const float*)d_in[10];
    const float* b_rm   = (const float*)d_in[11];
    const float* W_qm   = (const float*)d_in[12];
    const float* b_qm   = (const float*)d_in[13];
    const float* W_rr   = (const float*)d_in[14];
    const float* b_rr   = (const float*)d_in[15];
    const float* W_rg   = (const float*)d_in[16];
    const float* b_rg   = (const float*)d_in[17];
    const float* W_qg   = (const float*)d_in[18];
    const float* b_qg   = (const float*)d_in[19];
    const float* W_ms   = (const float*)d_in[20];
    // d_in[21] = b_ms: unused (softmax shift-invariant)

    // workspace layout (~38.9 MB, same footprint as round 0)
    char* w = (char*)d_ws;
    __bf16* acat  = (__bf16*)w;  w += (size_t)8192 * 1024 * 2;   // 16.78 MB (dead after g1)
    __bf16* qp    = (__bf16*)w;  w += (size_t)1024 * 512 * 2;
    __bf16* wcatT = (__bf16*)w;  w += (size_t)512 * 1024 * 2;
    __bf16* wdmT  = (__bf16*)w;  w += (size_t)512 * 512 * 2;
    __bf16* wqmT  = (__bf16*)w;  w += (size_t)512 * 512 * 2;
    __bf16* ctxb  = (__bf16*)w;  w += (size_t)8192 * 512 * 2;
    __bf16* ctxdm = (__bf16*)w;  w += (size_t)8192 * 512 * 2;
    float*  qmf   = (float*)w;   w += (size_t)1024 * 512 * 4;
    float*  rm    = (float*)w;   w += (size_t)NB * DIMD * 4;
    float*  rrt   = (float*)w;   w += (size_t)NB * DIMD * 4;
    float*  rbuf  = (float*)w;   w += (size_t)NB * DIMD * 4;
    float*  logit = (float*)w;   w += (size_t)NB * NS * 4;
    unsigned* ctr = (unsigned*)w; w += (size_t)NB * 4;
    // bf16 scan weights alias acat (written only after g1 consumed acat)
    __bf16* wrmbf = acat;
    __bf16* wrrbf = acat + (size_t)DIMD * DIMD;

    // prep
    k_prep_acat<<<8192, 256, 0, stream>>>(ctx_in, img, acat);
    k_cvt_bf16<<<512, 256, 0, stream>>>(q_in, qp, NT * NB * DIMD);
    k_transpose_w<<<dim3(16, 16), dim3(32, 8), 0, stream>>>(W_fc1, wcatT, 1024, 0);
    k_transpose_w<<<dim3(16, 16), dim3(32, 8), 0, stream>>>(W_fc2, wcatT, 1024, 512);
    k_transpose_w<<<dim3(16, 16), dim3(32, 8), 0, stream>>>(W_dm, wdmT, 512, 0);
    k_transpose_w<<<dim3(16, 16), dim3(32, 8), 0, stream>>>(W_qm, wqmT, 512, 0);

    // big GEMMs (LDS-staged bf16 MFMA)
    k_gemm_lds<<<dim3(64, 4), 256, 0, stream>>>(acat, wcatT, b_fc1, b_fc2, ctxb, 8192, 512, 1024, 0);
    k_cvt_bf16<<<512, 256, 0, stream>>>(W_rm, wrmbf, DIMD * DIMD);   // after g1: acat region free
    k_cvt_bf16<<<512, 256, 0, stream>>>(W_rr, wrrbf, DIMD * DIMD);
    k_gemm_lds<<<dim3(64, 4), 256, 0, stream>>>(ctxb, wdmT, b_dm, nullptr, ctxdm, 8192, 512, 512, 0);
    k_gemm_lds<<<dim3(8, 4), 256, 0, stream>>>(qp, wqmT, b_qm, nullptr, qmf, 1024, 512, 512, 1);

    // persistent scan (256 blocks <= half of machine capacity -> all co-resident)
    k_init<<<NB, DIMD, 0, stream>>>(b_rm, b_rr, rm, rrt, ctr);
    k_scan<<<256, 512, 0, stream>>>(ctxdm, ctxb, qmf, wrmbf, wrrbf, W_ms,
                                    b_rm, b_rr, logit, rm, rrt, rbuf, ctr);

    k_final2<<<64, 256, 0, stream>>>(rbuf, qh, W_rg, W_qg, b_rg, b_qg, (float*)d_out);
}